// Round 5
// baseline (97.894 us; speedup 1.0000x reference)
//
#include <hip/hip_runtime.h>
#include <hip/hip_bf16.h>

// MultiLinear: y[b,g,o] = sum_i x[b,g,i] * W[g,o,i] + bias[g,o]
// B=4096, G=16, DIN=512, DOUT=512, fp32 in/out.
// R5: 256x256 tile, 8 waves, double-buffered LDS; m201-style 4-phase/K-tile
// schedule (8 phases per 2 K-tiles): each phase {ds_read frag subtile ||
// staging work} -> lgkmcnt(0)+raw barrier -> setprio(1) 16xMFMA setprio(0)
// -> barrier. Reg-staged fp32 loads (T14) spread across P0/P1, fp32->bf16
// cvt + ds_write of next K-tile spread across P2/P3. XCD-chunked swizzle.

#define BATCH 4096
#define NGRP  16
#define DIN   512
#define DOUT  512

#define BM 256
#define BN 256
#define BK 64
#define NT (DIN / BK)   // 8 K-steps
#define LDK 72          // padded: 144 B row stride

typedef __bf16 bf16x8 __attribute__((ext_vector_type(8)));
typedef float  f32x4  __attribute__((ext_vector_type(4)));

__global__ __launch_bounds__(512, 2)
void MultiLinear_48498770706571_kernel(const float* __restrict__ X,
                                       const float* __restrict__ Wt,
                                       const float* __restrict__ Bias,
                                       float* __restrict__ Y) {
    // 512 blocks / 8 XCDs = 64 consecutive tiles (2 full groups) per XCD.
    const int bid = (blockIdx.x & 7) * 64 + (blockIdx.x >> 3);
    const int g   = bid >> 5;          // 32 tiles per group (16 m x 2 n)
    const int mt  = (bid >> 1) & 15;
    const int nt  = bid & 1;
    const int bm0 = mt * BM;
    const int bn0 = nt * BN;

    __shared__ __bf16 As[2][BM][LDK];
    __shared__ __bf16 Bs[2][BN][LDK];

    const int tid  = threadIdx.x;
    const int lane = tid & 63;
    const int w    = tid >> 6;        // 0..7
    const int wm   = (w >> 2) * 128;  // {0,128}
    const int wn   = (w & 3) * 64;    // {0,64,128,192}
    const int l15  = lane & 15;
    const int kq   = (lane >> 4) * 8; // k-offset within 32-subk

    // staging: 128 rows/pass (4 threads/row, 16 floats each), 2 passes.
    const int srow = tid >> 2;        // 0..127
    const int scol = (tid & 3) * 16;  // 0,16,32,48

    const float* pA = X + (size_t)(bm0 + srow) * (NGRP * DIN) + g * DIN + scol;
    const float* pB = Wt + (size_t)g * (DOUT * DIN) + (size_t)(bn0 + srow) * DIN + scol;
    const size_t strideA = (size_t)128 * (NGRP * DIN);
    const size_t strideB = (size_t)128 * DIN;

    f32x4 ra[2][4], rb[2][4];

#define ISSUE_A(k0)                                                        \
    do {                                                                   \
        const f32x4* qa0 = (const f32x4*)(pA + (k0));                      \
        const f32x4* qa1 = (const f32x4*)(pA + strideA + (k0));            \
        ra[0][0] = qa0[0]; ra[0][1] = qa0[1]; ra[0][2] = qa0[2]; ra[0][3] = qa0[3]; \
        ra[1][0] = qa1[0]; ra[1][1] = qa1[1]; ra[1][2] = qa1[2]; ra[1][3] = qa1[3]; \
    } while (0)

#define ISSUE_B(k0)                                                        \
    do {                                                                   \
        const f32x4* qb0 = (const f32x4*)(pB + (k0));                      \
        const f32x4* qb1 = (const f32x4*)(pB + strideB + (k0));            \
        rb[0][0] = qb0[0]; rb[0][1] = qb0[1]; rb[0][2] = qb0[2]; rb[0][3] = qb0[3]; \
        rb[1][0] = qb1[0]; rb[1][1] = qb1[1]; rb[1][2] = qb1[2]; rb[1][3] = qb1[3]; \
    } while (0)

#define CVT_WRITE_A(buf)                                                   \
    do {                                                                   \
        _Pragma("unroll")                                                  \
        for (int p = 0; p < 2; ++p) {                                      \
            bf16x8 v0, v1;                                                 \
            _Pragma("unroll")                                              \
            for (int j = 0; j < 4; ++j) {                                  \
                v0[j] = (__bf16)ra[p][0][j]; v0[j + 4] = (__bf16)ra[p][1][j]; \
                v1[j] = (__bf16)ra[p][2][j]; v1[j + 4] = (__bf16)ra[p][3][j]; \
            }                                                              \
            *(bf16x8*)&As[buf][p * 128 + srow][scol]     = v0;             \
            *(bf16x8*)&As[buf][p * 128 + srow][scol + 8] = v1;             \
        }                                                                  \
    } while (0)

#define CVT_WRITE_B(buf)                                                   \
    do {                                                                   \
        _Pragma("unroll")                                                  \
        for (int p = 0; p < 2; ++p) {                                      \
            bf16x8 u0, u1;                                                 \
            _Pragma("unroll")                                              \
            for (int j = 0; j < 4; ++j) {                                  \
                u0[j] = (__bf16)rb[p][0][j]; u0[j + 4] = (__bf16)rb[p][1][j]; \
                u1[j] = (__bf16)rb[p][2][j]; u1[j + 4] = (__bf16)rb[p][3][j]; \
            }                                                              \
            *(bf16x8*)&Bs[buf][p * 128 + srow][scol]     = u0;             \
            *(bf16x8*)&Bs[buf][p * 128 + srow][scol + 8] = u1;             \
        }                                                                  \
    } while (0)

// phase tail: drain own ds ops (cross-wave handoff; raw barrier won't),
// barrier, prioritized MFMA cluster, barrier.
#define PHASE_BAR()                                                        \
    do {                                                                   \
        asm volatile("s_waitcnt lgkmcnt(0)" ::: "memory");                 \
        __builtin_amdgcn_s_barrier();                                      \
    } while (0)

    f32x4 acc[8][4];
#pragma unroll
    for (int mi = 0; mi < 8; ++mi)
#pragma unroll
        for (int ni = 0; ni < 4; ++ni) acc[mi][ni] = f32x4{0.f, 0.f, 0.f, 0.f};

    // prologue: stage K-tile 0 into buf 0
    ISSUE_A(0);
    ISSUE_B(0);
    CVT_WRITE_A(0);
    CVT_WRITE_B(0);
    PHASE_BAR();

    for (int kt = 0; kt < NT; ++kt) {
        const int cur = kt & 1;
        const int nxt = cur ^ 1;
        const bool pre = (kt + 1 < NT);
        const int k0n = (kt + 1) * BK;

        bf16x8 af[4], bfr[4];

        // ---------- P0: frags subk0 m-lo + all B; issue A prefetch ----------
#pragma unroll
        for (int mi = 0; mi < 4; ++mi)
            af[mi] = *(const bf16x8*)&As[cur][wm + mi * 16 + l15][kq];
#pragma unroll
        for (int ni = 0; ni < 4; ++ni)
            bfr[ni] = *(const bf16x8*)&Bs[cur][wn + ni * 16 + l15][kq];
        if (pre) ISSUE_A(k0n);
        PHASE_BAR();
        __builtin_amdgcn_s_setprio(1);
#pragma unroll
        for (int mi = 0; mi < 4; ++mi)
#pragma unroll
            for (int ni = 0; ni < 4; ++ni)
                acc[mi][ni] = __builtin_amdgcn_mfma_f32_16x16x32_bf16(
                    af[mi], bfr[ni], acc[mi][ni], 0, 0, 0);
        __builtin_amdgcn_s_setprio(0);
        __builtin_amdgcn_s_barrier();

        // ---------- P1: frags subk0 m-hi; issue B prefetch ----------
#pragma unroll
        for (int mi = 0; mi < 4; ++mi)
            af[mi] = *(const bf16x8*)&As[cur][wm + 64 + mi * 16 + l15][kq];
        if (pre) ISSUE_B(k0n);
        PHASE_BAR();
        __builtin_amdgcn_s_setprio(1);
#pragma unroll
        for (int mi = 0; mi < 4; ++mi)
#pragma unroll
            for (int ni = 0; ni < 4; ++ni)
                acc[4 + mi][ni] = __builtin_amdgcn_mfma_f32_16x16x32_bf16(
                    af[mi], bfr[ni], acc[4 + mi][ni], 0, 0, 0);
        __builtin_amdgcn_s_setprio(0);
        __builtin_amdgcn_s_barrier();

        // ---------- P2: frags subk1 m-lo + all B; cvt+write A(next) ----------
#pragma unroll
        for (int mi = 0; mi < 4; ++mi)
            af[mi] = *(const bf16x8*)&As[cur][wm + mi * 16 + l15][32 + kq];
#pragma unroll
        for (int ni = 0; ni < 4; ++ni)
            bfr[ni] = *(const bf16x8*)&Bs[cur][wn + ni * 16 + l15][32 + kq];
        if (pre) CVT_WRITE_A(nxt);   // compiler-counted vmcnt wait on ra
        PHASE_BAR();
        __builtin_amdgcn_s_setprio(1);
#pragma unroll
        for (int mi = 0; mi < 4; ++mi)
#pragma unroll
            for (int ni = 0; ni < 4; ++ni)
                acc[mi][ni] = __builtin_amdgcn_mfma_f32_16x16x32_bf16(
                    af[mi], bfr[ni], acc[mi][ni], 0, 0, 0);
        __builtin_amdgcn_s_setprio(0);
        __builtin_amdgcn_s_barrier();

        // ---------- P3: frags subk1 m-hi; cvt+write B(next) ----------
#pragma unroll
        for (int mi = 0; mi < 4; ++mi)
            af[mi] = *(const bf16x8*)&As[cur][wm + 64 + mi * 16 + l15][32 + kq];
        if (pre) CVT_WRITE_B(nxt);
        PHASE_BAR();
        __builtin_amdgcn_s_setprio(1);
#pragma unroll
        for (int mi = 0; mi < 4; ++mi)
#pragma unroll
            for (int ni = 0; ni < 4; ++ni)
                acc[4 + mi][ni] = __builtin_amdgcn_mfma_f32_16x16x32_bf16(
                    af[mi], bfr[ni], acc[4 + mi][ni], 0, 0, 0);
        __builtin_amdgcn_s_setprio(0);
        __builtin_amdgcn_s_barrier();
    }

    // epilogue: C/D layout col = lane&15, row = (lane>>4)*4 + j (verified R1)
    const int r0 = (lane >> 4) * 4;
    const int c  = lane & 15;
    float bias_n[4];
#pragma unroll
    for (int ni = 0; ni < 4; ++ni)
        bias_n[ni] = Bias[g * DOUT + bn0 + wn + ni * 16 + c];
#pragma unroll
    for (int mi = 0; mi < 8; ++mi) {
#pragma unroll
        for (int j = 0; j < 4; ++j) {
            const int row = bm0 + wm + mi * 16 + r0 + j;
            float* yrow = Y + (size_t)row * (NGRP * DOUT) + g * DOUT + bn0 + wn;
#pragma unroll
            for (int ni = 0; ni < 4; ++ni)
                yrow[ni * 16 + c] = acc[mi][ni][j] + bias_n[ni];
        }
    }
#undef ISSUE_A
#undef ISSUE_B
#undef CVT_WRITE_A
#undef CVT_WRITE_B
#undef PHASE_BAR
}

extern "C" void kernel_launch(void* const* d_in, const int* in_sizes, int n_in,
                              void* d_out, int out_size, void* d_ws, size_t ws_size,
                              hipStream_t stream) {
    const float* X    = (const float*)d_in[0];
    const float* Wt   = (const float*)d_in[1];
    const float* Bias = (const float*)d_in[2];
    float* Y          = (float*)d_out;

    const int grid = NGRP * (BATCH / BM) * (DOUT / BN);  // 512
    MultiLinear_48498770706571_kernel<<<grid, 512, 0, stream>>>(X, Wt, Bias, Y);
}